// Round 1
// baseline (121.845 us; speedup 1.0000x reference)
//
#include <hip/hip_runtime.h>
#include <math.h>

#define T 8
#define C 16
#define H 16

// ---------------- Kernel 1: quantum expectation sum ----------------
__global__ __launch_bounds__(256) void qnn_kernel(
    const float* __restrict__ x,      // [B,8,16]
    const float* __restrict__ Wq,     // [16,16]
    const float* __restrict__ qw,     // [12]
    float* __restrict__ evsum,        // [1] accumulator (pre-zeroed)
    int B)
{
  __shared__ float wqm[16];
  __shared__ float wsum[4];
  int tid = threadIdx.x;
  if (tid < 16) {
    float s = 0.f;
    #pragma unroll
    for (int h = 0; h < 16; ++h) s += Wq[tid*16 + h];
    wqm[tid] = s * (1.0f/16.0f);
  }
  __syncthreads();

  int b = blockIdx.x * 256 + tid;
  float ev = 0.f;
  if (b < B) {
    const float* xb = x + (size_t)b * (T*C);
    float f[4];
    #pragma unroll
    for (int j = 0; j < 4; ++j) {
      float d = 0.f;
      #pragma unroll
      for (int c4 = 0; c4 < 4; ++c4) {
        float4 xv = ((const float4*)(xb + j*16))[c4];
        d += xv.x*wqm[c4*4+0] + xv.y*wqm[c4*4+1] + xv.z*wqm[c4*4+2] + xv.w*wqm[c4*4+3];
      }
      f[j] = tanhf(d);
    }
    const float PI_F = 3.14159265358979323846f;
    float l30 = 2.f*(PI_F - f[3])*(PI_F - f[0]);
    float l01 = 2.f*(PI_F - f[0])*(PI_F - f[1]);
    float l12 = 2.f*(PI_F - f[1])*(PI_F - f[2]);
    float l23 = 2.f*(PI_F - f[2])*(PI_F - f[3]);
    float sr[16], si[16];
    // Feature map: H^4 then all-diagonal phases -> amp_z = 0.25*e^{i phi_z}
    #pragma unroll
    for (int z = 0; z < 16; ++z) {
      int b0 = (z>>3)&1, b1 = (z>>2)&1, b2 = (z>>1)&1, b3 = z&1;
      float ph = 2.f*(f[0]*b0 + f[1]*b1 + f[2]*b2 + f[3]*b3)
               + l30*(float)(b3^b0) + l01*(float)(b0^b1)
               + l12*(float)(b1^b2) + l23*(float)(b2^b3);
      float cp, sp;
      __sincosf(ph, &sp, &cp);
      sr[z] = 0.25f * cp;
      si[z] = 0.25f * sp;
    }
    // RealAmplitudes(reps=2, circular): 3 RY layers, CX chain after layers 0,1
    #pragma unroll
    for (int rep = 0; rep < 3; ++rep) {
      #pragma unroll
      for (int q = 0; q < 4; ++q) {
        float th = 0.5f * qw[rep*4 + q];
        float cth = cosf(th), sth = sinf(th);
        int m = 8 >> q;
        #pragma unroll
        for (int z = 0; z < 16; ++z) {
          if (z & m) continue;
          int z1 = z | m;
          float a0r = sr[z],  a0i = si[z];
          float a1r = sr[z1], a1i = si[z1];
          sr[z]  = cth*a0r - sth*a1r;  si[z]  = cth*a0i - sth*a1i;
          sr[z1] = sth*a0r + cth*a1r;  si[z1] = sth*a0i + cth*a1i;
        }
      }
      if (rep < 2) {
        // CX pairs (control,target): (3,0),(0,1),(1,2),(2,3)
        #pragma unroll
        for (int p = 0; p < 4; ++p) {
          const int ctl[4] = {3,0,1,2};
          const int tgt[4] = {0,1,2,3};
          int mc = 8 >> ctl[p], mt = 8 >> tgt[p];
          #pragma unroll
          for (int z = 0; z < 16; ++z) {
            if ((z & mc) && !(z & mt)) {
              int z1 = z | mt;
              float tr = sr[z]; sr[z] = sr[z1]; sr[z1] = tr;
              float ti = si[z]; si[z] = si[z1]; si[z1] = ti;
            }
          }
        }
      }
    }
    #pragma unroll
    for (int z = 0; z < 16; ++z) {
      float p = sr[z]*sr[z] + si[z]*si[z];
      ev += (__popc(z) & 1) ? -p : p;
    }
  }
  // block reduction -> one atomic
  #pragma unroll
  for (int off = 32; off > 0; off >>= 1) ev += __shfl_down(ev, off, 64);
  if ((tid & 63) == 0) wsum[tid >> 6] = ev;
  __syncthreads();
  if (tid == 0) atomicAdd(evsum, wsum[0] + wsum[1] + wsum[2] + wsum[3]);
}

// ---------------- Kernel 2: attention with scalar enhancement ----------------
#define GB 32  // batches per block (256 threads / 8 rows)
__global__ __launch_bounds__(256) void attn_kernel(
    const float* __restrict__ x,
    const float* __restrict__ Wk,
    const float* __restrict__ Wq,
    const float* __restrict__ Wv,
    const float* __restrict__ evsum,
    const float* __restrict__ qscale,
    float* __restrict__ out,
    float invB)
{
  __shared__ float ks[GB][132];  // pad 132: conflict-free 8-way-broadcast reads
  __shared__ float vs[GB][132];
  int tid = threadIdx.x;
  int g = tid >> 3, t = tid & 7;
  size_t b = (size_t)blockIdx.x * GB + g;
  const float* xp = x + (b*T + t) * C;

  float xr[16];
  #pragma unroll
  for (int i = 0; i < 4; ++i) {
    float4 v4 = ((const float4*)xp)[i];
    xr[4*i+0] = v4.x; xr[4*i+1] = v4.y; xr[4*i+2] = v4.z; xr[4*i+3] = v4.w;
  }

  float kr[16], qr[16], vr[16];
  #pragma unroll
  for (int h = 0; h < 16; ++h) { kr[h] = 0.f; qr[h] = 0.f; vr[h] = 0.f; }
  // W addresses are uniform (compile-time) -> scalar loads, SGPR broadcast
  #pragma unroll
  for (int c = 0; c < 16; ++c) {
    float xc = xr[c];
    #pragma unroll
    for (int h = 0; h < 16; ++h) {
      kr[h] += xc * Wk[c*16 + h];
      qr[h] += xc * Wq[c*16 + h];
      vr[h] += xc * Wv[c*16 + h];
    }
  }
  #pragma unroll
  for (int i = 0; i < 4; ++i) {
    ((float4*)&ks[g][t*16])[i] = make_float4(kr[4*i], kr[4*i+1], kr[4*i+2], kr[4*i+3]);
    ((float4*)&vs[g][t*16])[i] = make_float4(vr[4*i], vr[4*i+1], vr[4*i+2], vr[4*i+3]);
  }
  __syncthreads();

  float enh = qscale[0] / (1.f + __expf(-evsum[0] * invB));

  float sc[8];
  #pragma unroll
  for (int s = 0; s < 8; ++s) {
    float d = 0.f;
    #pragma unroll
    for (int i = 0; i < 4; ++i) {
      float4 kv = ((const float4*)&ks[g][s*16])[i];
      d += qr[4*i]*kv.x + qr[4*i+1]*kv.y + qr[4*i+2]*kv.z + qr[4*i+3]*kv.w;
    }
    sc[s] = d * 0.25f;  // C^-0.5 = 1/4
  }
  // causal softmax over s<=t (thread-local)
  float m = sc[0];
  #pragma unroll
  for (int s = 1; s < 8; ++s) if (s <= t) m = fmaxf(m, sc[s]);
  float w8[8], sum = 0.f;
  #pragma unroll
  for (int s = 0; s < 8; ++s) {
    float e = (s <= t) ? __expf(sc[s] - m) : 0.f;
    w8[s] = e; sum += e;
  }
  float inv = 1.f / sum;
  #pragma unroll
  for (int s = 0; s < 8; ++s) w8[s] = w8[s]*inv + enh;

  float acc[16];
  #pragma unroll
  for (int h = 0; h < 16; ++h) acc[h] = 0.f;
  #pragma unroll
  for (int s = 0; s < 8; ++s) {
    float w = w8[s];
    #pragma unroll
    for (int i = 0; i < 4; ++i) {
      float4 vv = ((const float4*)&vs[g][s*16])[i];
      acc[4*i+0] += w*vv.x; acc[4*i+1] += w*vv.y;
      acc[4*i+2] += w*vv.z; acc[4*i+3] += w*vv.w;
    }
  }
  float* op = out + (b*T + t) * C;
  #pragma unroll
  for (int i = 0; i < 4; ++i)
    ((float4*)op)[i] = make_float4(acc[4*i], acc[4*i+1], acc[4*i+2], acc[4*i+3]);
}

extern "C" void kernel_launch(void* const* d_in, const int* in_sizes, int n_in,
                              void* d_out, int out_size, void* d_ws, size_t ws_size,
                              hipStream_t stream) {
  const float* x  = (const float*)d_in[0];
  const float* Wk = (const float*)d_in[1];
  const float* Wq = (const float*)d_in[2];
  const float* Wv = (const float*)d_in[3];
  const float* qw = (const float*)d_in[4];
  const float* qs = (const float*)d_in[5];
  float* out = (float*)d_out;
  float* evsum = (float*)d_ws;

  int B = in_sizes[0] / (T * C);  // 65536

  hipMemsetAsync(evsum, 0, sizeof(float), stream);
  qnn_kernel<<<(B + 255) / 256, 256, 0, stream>>>(x, Wq, qw, evsum, B);
  attn_kernel<<<B / GB, 256, 0, stream>>>(x, Wk, Wq, Wv, evsum, qs, out,
                                          1.0f / (float)B);
}

// Round 2
// 101.628 us; speedup vs baseline: 1.1989x; 1.1989x over previous
//
#include <hip/hip_runtime.h>
#include <hip/hip_bf16.h>
#include <math.h>

#define T 8
#define C 16

typedef __attribute__((ext_vector_type(4))) float f32x4;
typedef __attribute__((ext_vector_type(8))) short s16x8;

__device__ inline unsigned int pkbf(float a, float b) {
  __hip_bfloat162 h = __float22bfloat162_rn(make_float2(a, b));
  unsigned int u; __builtin_memcpy(&u, &h, 4); return u;
}
// Build an 8-elem bf16 frag: elems 0-3 = RNE(bf16) of a0..a3, elems 4-7 = 0.
__device__ inline s16x8 mk_frag(float a0, float a1, float a2, float a3) {
  union { s16x8 v; unsigned int u[4]; } f;
  f.u[0] = pkbf(a0, a1); f.u[1] = pkbf(a2, a3); f.u[2] = 0u; f.u[3] = 0u;
  return f.v;
}

// ---------------- Kernel 1: quantum expectation sum ----------------
__global__ __launch_bounds__(256) void qnn_kernel(
    const float* __restrict__ x, const float* __restrict__ Wq,
    const float* __restrict__ qw, float* __restrict__ evsum, int B)
{
  __shared__ float wqm[16];
  __shared__ float wsum[4];
  int tid = threadIdx.x;
  if (tid < 16) {
    float s = 0.f;
    #pragma unroll
    for (int h = 0; h < 16; ++h) s += Wq[tid*16 + h];
    wqm[tid] = s * (1.0f/16.0f);
  }
  __syncthreads();

  int b = blockIdx.x * 256 + tid;
  float ev = 0.f;
  if (b < B) {
    const float* xb = x + (size_t)b * (T*C);
    float f[4];
    #pragma unroll
    for (int j = 0; j < 4; ++j) {
      float d = 0.f;
      #pragma unroll
      for (int c4 = 0; c4 < 4; ++c4) {
        float4 xv = ((const float4*)(xb + j*16))[c4];
        d += xv.x*wqm[c4*4+0] + xv.y*wqm[c4*4+1] + xv.z*wqm[c4*4+2] + xv.w*wqm[c4*4+3];
      }
      float e2 = __expf(2.f*d);               // tanh via exp
      f[j] = 1.f - 2.f/(e2 + 1.f);
    }
    const float PI_F = 3.14159265358979323846f;
    float l30 = 2.f*(PI_F - f[3])*(PI_F - f[0]);
    float l01 = 2.f*(PI_F - f[0])*(PI_F - f[1]);
    float l12 = 2.f*(PI_F - f[1])*(PI_F - f[2]);
    float l23 = 2.f*(PI_F - f[2])*(PI_F - f[3]);
    float sr[16], si[16];
    #pragma unroll
    for (int z = 0; z < 16; ++z) {
      int b0 = (z>>3)&1, b1 = (z>>2)&1, b2 = (z>>1)&1, b3 = z&1;
      float ph = 2.f*(f[0]*b0 + f[1]*b1 + f[2]*b2 + f[3]*b3)
               + l30*(float)(b3^b0) + l01*(float)(b0^b1)
               + l12*(float)(b1^b2) + l23*(float)(b2^b3);
      float cp, sp;
      __sincosf(ph, &sp, &cp);
      sr[z] = 0.25f * cp; si[z] = 0.25f * sp;
    }
    #pragma unroll
    for (int rep = 0; rep < 3; ++rep) {
      #pragma unroll
      for (int q = 0; q < 4; ++q) {
        float th = 0.5f * qw[rep*4 + q];
        float cth = cosf(th), sth = sinf(th);
        int m = 8 >> q;
        #pragma unroll
        for (int z = 0; z < 16; ++z) {
          if (z & m) continue;
          int z1 = z | m;
          float a0r = sr[z],  a0i = si[z];
          float a1r = sr[z1], a1i = si[z1];
          sr[z]  = cth*a0r - sth*a1r;  si[z]  = cth*a0i - sth*a1i;
          sr[z1] = sth*a0r + cth*a1r;  si[z1] = sth*a0i + cth*a1i;
        }
      }
      if (rep < 2) {
        #pragma unroll
        for (int p = 0; p < 4; ++p) {
          const int ctl[4] = {3,0,1,2};
          const int tgt[4] = {0,1,2,3};
          int mc = 8 >> ctl[p], mt = 8 >> tgt[p];
          #pragma unroll
          for (int z = 0; z < 16; ++z) {
            if ((z & mc) && !(z & mt)) {
              int z1 = z | mt;
              float tr = sr[z]; sr[z] = sr[z1]; sr[z1] = tr;
              float ti = si[z]; si[z] = si[z1]; si[z1] = ti;
            }
          }
        }
      }
    }
    #pragma unroll
    for (int z = 0; z < 16; ++z) {
      float p = sr[z]*sr[z] + si[z]*si[z];
      ev += (__popc(z) & 1) ? -p : p;
    }
  }
  #pragma unroll
  for (int off = 32; off > 0; off >>= 1) ev += __shfl_down(ev, off, 64);
  if ((tid & 63) == 0) wsum[tid >> 6] = ev;
  __syncthreads();
  if (tid == 0) atomicAdd(evsum, wsum[0] + wsum[1] + wsum[2] + wsum[3]);
}

// ---------------- Kernel 2: MFMA attention, 2 batches per 16x16 tile ----------------
// Tile = 16 rows (2 batches x 8 t) x 16 ch. S^T = x*(0.25*Wq@Wk^T)*x^T via 2 MFMAs,
// V = x@Wv, O = w@V. C-layout (col=lane&15,row=4g+reg) repacked reg->elem serves as
// A-frag of D^T / B-frag of D, so no LDS transposes. enh added to all valid s cols.
#define TPW 4
__global__ __launch_bounds__(256) void attn_mfma(
    const float* __restrict__ x,
    const float* __restrict__ Wk, const float* __restrict__ Wq,
    const float* __restrict__ Wv,
    const float* __restrict__ evsum, const float* __restrict__ qscale,
    float* __restrict__ out, float invB, int ntiles)
{
  const int lane = threadIdx.x & 63;
  const int wid  = threadIdx.x >> 6;
  const int r16  = lane & 15;
  const int g    = lane >> 4;

  const float enh = qscale[0] / (1.f + __expf(-evsum[0] * invB));

  // Hoisted fragments (placement: lane l elem j <-> k-index 4g+j)
  const float4 wq4 = *(const float4*)(Wq + r16*16 + 4*g);
  const float4 wk4 = *(const float4*)(Wk + r16*16 + 4*g);
  s16x8 aWq = mk_frag(wq4.x, wq4.y, wq4.z, wq4.w);   // A = Wq  [c][h]
  s16x8 bWk = mk_frag(wk4.x, wk4.y, wk4.z, wk4.w);   // B = Wk^T [h][c']
  f32x4 zero = {0.f, 0.f, 0.f, 0.f};
  f32x4 M = __builtin_amdgcn_mfma_f32_16x16x32_bf16(aWq, bWk, zero, 0, 0, 0);
  // aMt = A-frag of 0.25*M^T (scale C^-0.5=1/4 folded here)
  s16x8 aMt = mk_frag(0.25f*M[0], 0.25f*M[1], 0.25f*M[2], 0.25f*M[3]);
  const float wv0 = Wv[(4*g+0)*16 + r16];
  const float wv1 = Wv[(4*g+1)*16 + r16];
  const float wv2 = Wv[(4*g+2)*16 + r16];
  const float wv3 = Wv[(4*g+3)*16 + r16];
  s16x8 bWv = mk_frag(wv0, wv1, wv2, wv3);            // B = Wv [c][h]

  const bool validL = ((r16 >> 3) == (g >> 1));       // own-batch (t,s) block

  long tile0 = ((long)blockIdx.x * 4 + wid) * TPW;
  if (tile0 >= ntiles) return;
  const float* xp = x + tile0*256 + r16*16 + 4*g;
  float* op0 = out + tile0*256 + r16;

  float4 xv = *(const float4*)xp;
  #pragma unroll
  for (int it = 0; it < TPW; ++it) {
    float4 xn = xv;
    if (it + 1 < TPW) xn = *(const float4*)(xp + (it+1)*256);

    s16x8 ax = mk_frag(xv.x, xv.y, xv.z, xv.w);       // A = x rows / B = x^T
    f32x4 V  = __builtin_amdgcn_mfma_f32_16x16x32_bf16(ax, bWv, zero, 0,0,0);   // [s][h]
    f32x4 t2 = __builtin_amdgcn_mfma_f32_16x16x32_bf16(aMt, ax, zero, 0,0,0);   // 0.25(xM)^T
    s16x8 bt = mk_frag(t2[0], t2[1], t2[2], t2[3]);
    f32x4 St = __builtin_amdgcn_mfma_f32_16x16x32_bf16(ax, bt, zero, 0,0,0);    // S^T [s][t], pre-scaled

    // softmax over s for column t=r16; s_j = 4g+j; causal s<=t within own batch
    float m = -INFINITY;
    #pragma unroll
    for (int j = 0; j < 4; ++j)
      if (validL && (4*g + j) <= r16) m = fmaxf(m, St[j]);
    m = fmaxf(m, __shfl_xor(m, 16));
    m = fmaxf(m, __shfl_xor(m, 32));
    float e[4], d = 0.f;
    #pragma unroll
    for (int j = 0; j < 4; ++j) {
      e[j] = (validL && (4*g + j) <= r16) ? __expf(St[j] - m) : 0.f;
      d += e[j];
    }
    d += __shfl_xor(d, 16);
    d += __shfl_xor(d, 32);
    float inv = 1.f / d;
    float w0 = e[0]*inv, w1 = e[1]*inv, w2 = e[2]*inv, w3 = e[3]*inv;
    if (validL) { w0 += enh; w1 += enh; w2 += enh; w3 += enh; }  // enh on all 8 own cols

    s16x8 aw = mk_frag(w0, w1, w2, w3);               // A = w [t][s]
    s16x8 bV = mk_frag(V[0], V[1], V[2], V[3]);       // B = V [s][h]
    f32x4 O  = __builtin_amdgcn_mfma_f32_16x16x32_bf16(aw, bV, zero, 0,0,0);    // [t][h]

    float* op = op0 + it*256;
    op[(4*g + 0)*16] = O[0];
    op[(4*g + 1)*16] = O[1];
    op[(4*g + 2)*16] = O[2];
    op[(4*g + 3)*16] = O[3];

    xv = xn;
  }
}

extern "C" void kernel_launch(void* const* d_in, const int* in_sizes, int n_in,
                              void* d_out, int out_size, void* d_ws, size_t ws_size,
                              hipStream_t stream) {
  const float* x  = (const float*)d_in[0];
  const float* Wk = (const float*)d_in[1];
  const float* Wq = (const float*)d_in[2];
  const float* Wv = (const float*)d_in[3];
  const float* qw = (const float*)d_in[4];
  const float* qs = (const float*)d_in[5];
  float* out = (float*)d_out;
  float* evsum = (float*)d_ws;

  int B = in_sizes[0] / (T * C);          // 65536
  int ntiles = B / 2;                     // 2 batches per 16x16 tile

  hipMemsetAsync(evsum, 0, sizeof(float), stream);
  qnn_kernel<<<(B + 255) / 256, 256, 0, stream>>>(x, Wq, qw, evsum, B);
  attn_mfma<<<ntiles / (4 * TPW), 256, 0, stream>>>(x, Wk, Wq, Wv, evsum, qs,
                                                    out, 1.0f / (float)B, ntiles);
}

// Round 3
// 99.469 us; speedup vs baseline: 1.2250x; 1.0217x over previous
//
#include <hip/hip_runtime.h>
#include <hip/hip_bf16.h>
#include <math.h>

#define T 8
#define C 16

typedef __attribute__((ext_vector_type(4))) float f32x4;
typedef __attribute__((ext_vector_type(8))) short s16x8;

__device__ inline unsigned int pkbf(float a, float b) {
  __hip_bfloat162 h = __float22bfloat162_rn(make_float2(a, b));
  unsigned int u; __builtin_memcpy(&u, &h, 4); return u;
}
// 8-elem bf16 frag: elems 0-3 = RNE(bf16) of a0..a3, elems 4-7 = 0.
__device__ inline s16x8 mk_frag(float a0, float a1, float a2, float a3) {
  union { s16x8 v; unsigned int u[4]; } f;
  f.u[0] = pkbf(a0, a1); f.u[1] = pkbf(a2, a3); f.u[2] = 0u; f.u[3] = 0u;
  return f.v;
}

// ---------------- Kernel 1: quantum expectation, per-block partial sums ----------------
__global__ __launch_bounds__(256) void qnn_kernel(
    const float* __restrict__ x, const float* __restrict__ Wq,
    const float* __restrict__ qw, float* __restrict__ partial, int B)
{
  __shared__ float wqm[16];
  __shared__ float wsum[4];
  int tid = threadIdx.x;
  if (tid < 16) {
    float s = 0.f;
    #pragma unroll
    for (int h = 0; h < 16; ++h) s += Wq[tid*16 + h];
    wqm[tid] = s * (1.0f/16.0f);
  }
  __syncthreads();

  int b = blockIdx.x * 256 + tid;
  float ev = 0.f;
  if (b < B) {
    const float* xb = x + (size_t)b * (T*C);
    float f[4];
    #pragma unroll
    for (int j = 0; j < 4; ++j) {
      float d = 0.f;
      #pragma unroll
      for (int c4 = 0; c4 < 4; ++c4) {
        float4 xv = ((const float4*)(xb + j*16))[c4];
        d += xv.x*wqm[c4*4+0] + xv.y*wqm[c4*4+1] + xv.z*wqm[c4*4+2] + xv.w*wqm[c4*4+3];
      }
      float e2 = __expf(2.f*d);               // tanh via exp
      f[j] = 1.f - 2.f/(e2 + 1.f);
    }
    const float PI_F = 3.14159265358979323846f;
    float l30 = 2.f*(PI_F - f[3])*(PI_F - f[0]);
    float l01 = 2.f*(PI_F - f[0])*(PI_F - f[1]);
    float l12 = 2.f*(PI_F - f[1])*(PI_F - f[2]);
    float l23 = 2.f*(PI_F - f[2])*(PI_F - f[3]);
    float sr[16], si[16];
    // Feature map: H^4 then all-diagonal phases -> amp_z = 0.25*e^{i phi_z}
    #pragma unroll
    for (int z = 0; z < 16; ++z) {
      int b0 = (z>>3)&1, b1 = (z>>2)&1, b2 = (z>>1)&1, b3 = z&1;
      float ph = 2.f*(f[0]*b0 + f[1]*b1 + f[2]*b2 + f[3]*b3)
               + l30*(float)(b3^b0) + l01*(float)(b0^b1)
               + l12*(float)(b1^b2) + l23*(float)(b2^b3);
      float cp, sp;
      __sincosf(ph, &sp, &cp);
      sr[z] = 0.25f * cp; si[z] = 0.25f * sp;
    }
    // RealAmplitudes(reps=2, circular): hw sincos for the 12 RY angles
    #pragma unroll
    for (int rep = 0; rep < 3; ++rep) {
      #pragma unroll
      for (int q = 0; q < 4; ++q) {
        float sth, cth;
        __sincosf(0.5f * qw[rep*4 + q], &sth, &cth);
        int m = 8 >> q;
        #pragma unroll
        for (int z = 0; z < 16; ++z) {
          if (z & m) continue;
          int z1 = z | m;
          float a0r = sr[z],  a0i = si[z];
          float a1r = sr[z1], a1i = si[z1];
          sr[z]  = cth*a0r - sth*a1r;  si[z]  = cth*a0i - sth*a1i;
          sr[z1] = sth*a0r + cth*a1r;  si[z1] = sth*a0i + cth*a1i;
        }
      }
      if (rep < 2) {
        #pragma unroll
        for (int p = 0; p < 4; ++p) {
          const int ctl[4] = {3,0,1,2};
          const int tgt[4] = {0,1,2,3};
          int mc = 8 >> ctl[p], mt = 8 >> tgt[p];
          #pragma unroll
          for (int z = 0; z < 16; ++z) {
            if ((z & mc) && !(z & mt)) {
              int z1 = z | mt;
              float tr = sr[z]; sr[z] = sr[z1]; sr[z1] = tr;
              float ti = si[z]; si[z] = si[z1]; si[z1] = ti;
            }
          }
        }
      }
    }
    #pragma unroll
    for (int z = 0; z < 16; ++z) {
      float p = sr[z]*sr[z] + si[z]*si[z];
      ev += (__popc(z) & 1) ? -p : p;
    }
  }
  // block reduction -> plain store of the block partial (no memset, no atomic)
  #pragma unroll
  for (int off = 32; off > 0; off >>= 1) ev += __shfl_down(ev, off, 64);
  if ((tid & 63) == 0) wsum[tid >> 6] = ev;
  __syncthreads();
  if (tid == 0) partial[blockIdx.x] = wsum[0] + wsum[1] + wsum[2] + wsum[3];
}

// ---------------- Kernel 2: MFMA attention, 2 batches per 16x16 tile ----------------
// Tile = 16 rows (2 batches x 8 t) x 16 ch. S^T = x*(0.25*Wq@Wk^T)*x^T via 2 MFMAs,
// V = x@Wv, O = w@V. C-layout (col=lane&15,row=4g+reg) repacked reg->elem serves as
// A-frag of D^T / B-frag of D, so no LDS transposes. enh added to all valid s cols.
#define TPW 4
#define NPART 256
__global__ __launch_bounds__(256) void attn_mfma(
    const float* __restrict__ x,
    const float* __restrict__ Wk, const float* __restrict__ Wq,
    const float* __restrict__ Wv,
    const float* __restrict__ partial, const float* __restrict__ qscale,
    float* __restrict__ out, float invB, int ntiles)
{
  __shared__ float red[4];
  const int tid  = threadIdx.x;
  const int lane = tid & 63;
  const int wid  = tid >> 6;
  const int r16  = lane & 15;
  const int g    = lane >> 4;

  // reduce the 256 qnn block partials (L2-resident, ~1KB per block)
  float pv = partial[tid];
  #pragma unroll
  for (int off = 32; off > 0; off >>= 1) pv += __shfl_down(pv, off, 64);
  if (lane == 0) red[wid] = pv;
  __syncthreads();
  const float evs = red[0] + red[1] + red[2] + red[3];
  const float enh = qscale[0] / (1.f + __expf(-evs * invB));

  // Hoisted fragments (placement: lane l elem j <-> k-index 4g+j)
  const float4 wq4 = *(const float4*)(Wq + r16*16 + 4*g);
  const float4 wk4 = *(const float4*)(Wk + r16*16 + 4*g);
  s16x8 aWq = mk_frag(wq4.x, wq4.y, wq4.z, wq4.w);   // A = Wq  [c][h]
  s16x8 bWk = mk_frag(wk4.x, wk4.y, wk4.z, wk4.w);   // B = Wk^T [h][c']
  f32x4 zero = {0.f, 0.f, 0.f, 0.f};
  f32x4 M = __builtin_amdgcn_mfma_f32_16x16x32_bf16(aWq, bWk, zero, 0, 0, 0);
  // aMt = A-frag of 0.25*M^T (scale C^-0.5=1/4 folded here)
  s16x8 aMt = mk_frag(0.25f*M[0], 0.25f*M[1], 0.25f*M[2], 0.25f*M[3]);
  const float wv0 = Wv[(4*g+0)*16 + r16];
  const float wv1 = Wv[(4*g+1)*16 + r16];
  const float wv2 = Wv[(4*g+2)*16 + r16];
  const float wv3 = Wv[(4*g+3)*16 + r16];
  s16x8 bWv = mk_frag(wv0, wv1, wv2, wv3);            // B = Wv [c][h]

  const bool validL = ((r16 >> 3) == (g >> 1));       // own-batch (t,s) block

  long tile0 = ((long)blockIdx.x * 4 + wid) * TPW;
  if (tile0 >= ntiles) return;
  const float* xp = x + tile0*256 + r16*16 + 4*g;
  float* op0 = out + tile0*256 + r16;

  float4 xv = *(const float4*)xp;
  #pragma unroll
  for (int it = 0; it < TPW; ++it) {
    float4 xn = xv;
    if (it + 1 < TPW) xn = *(const float4*)(xp + (it+1)*256);

    s16x8 ax = mk_frag(xv.x, xv.y, xv.z, xv.w);       // A = x rows / B = x^T
    f32x4 V  = __builtin_amdgcn_mfma_f32_16x16x32_bf16(ax, bWv, zero, 0,0,0);   // [s][h]
    f32x4 t2 = __builtin_amdgcn_mfma_f32_16x16x32_bf16(aMt, ax, zero, 0,0,0);   // 0.25(xM)^T
    s16x8 bt = mk_frag(t2[0], t2[1], t2[2], t2[3]);
    f32x4 St = __builtin_amdgcn_mfma_f32_16x16x32_bf16(ax, bt, zero, 0,0,0);    // S^T [s][t], pre-scaled

    // softmax over s for column t=r16; s_j = 4g+j; causal s<=t within own batch
    float m = -INFINITY;
    #pragma unroll
    for (int j = 0; j < 4; ++j)
      if (validL && (4*g + j) <= r16) m = fmaxf(m, St[j]);
    m = fmaxf(m, __shfl_xor(m, 16));
    m = fmaxf(m, __shfl_xor(m, 32));
    float e[4], d = 0.f;
    #pragma unroll
    for (int j = 0; j < 4; ++j) {
      e[j] = (validL && (4*g + j) <= r16) ? __expf(St[j] - m) : 0.f;
      d += e[j];
    }
    d += __shfl_xor(d, 16);
    d += __shfl_xor(d, 32);
    float inv = 1.f / d;
    float w0 = e[0]*inv, w1 = e[1]*inv, w2 = e[2]*inv, w3 = e[3]*inv;
    if (validL) { w0 += enh; w1 += enh; w2 += enh; w3 += enh; }  // enh on all 8 own cols

    s16x8 aw = mk_frag(w0, w1, w2, w3);               // A = w [t][s]
    s16x8 bV = mk_frag(V[0], V[1], V[2], V[3]);       // B = V [s][h]
    f32x4 O  = __builtin_amdgcn_mfma_f32_16x16x32_bf16(aw, bV, zero, 0,0,0);    // [t][h]

    float* op = op0 + it*256;
    op[(4*g + 0)*16] = O[0];
    op[(4*g + 1)*16] = O[1];
    op[(4*g + 2)*16] = O[2];
    op[(4*g + 3)*16] = O[3];

    xv = xn;
  }
}

extern "C" void kernel_launch(void* const* d_in, const int* in_sizes, int n_in,
                              void* d_out, int out_size, void* d_ws, size_t ws_size,
                              hipStream_t stream) {
  const float* x  = (const float*)d_in[0];
  const float* Wk = (const float*)d_in[1];
  const float* Wq = (const float*)d_in[2];
  const float* Wv = (const float*)d_in[3];
  const float* qw = (const float*)d_in[4];
  const float* qs = (const float*)d_in[5];
  float* out = (float*)d_out;
  float* partial = (float*)d_ws;      // 256 floats, fully overwritten by qnn

  int B = in_sizes[0] / (T * C);      // 65536
  int ntiles = B / 2;                 // 2 batches per 16x16 tile

  qnn_kernel<<<B / 256, 256, 0, stream>>>(x, Wq, qw, partial, B);
  attn_mfma<<<ntiles / (4 * TPW), 256, 0, stream>>>(x, Wk, Wq, Wv, partial, qs,
                                                    out, 1.0f / (float)B, ntiles);
}